// Round 1
// baseline (1011.486 us; speedup 1.0000x reference)
//
#include <hip/hip_runtime.h>

#define N_NODES   50000
#define N_EDGES   1600000
#define FDIM_IN   128
#define HDIM      160
#define N_GRAPHS  512
#define BN_EPS    1e-5f

// ---------------- edge sort (counting sort by dst) ----------------

__global__ __launch_bounds__(256) void hist_kernel(const int* __restrict__ dst,
                                                   int* __restrict__ cnt, int E) {
    int e = blockIdx.x * 256 + threadIdx.x;
    if (e < E) atomicAdd(&cnt[dst[e]], 1);
}

__global__ __launch_bounds__(256) void inv_kernel(const int* __restrict__ cnt,
                                                  float* __restrict__ inv, int n) {
    int i = blockIdx.x * 256 + threadIdx.x;
    if (i < n) inv[i] = rsqrtf((float)(cnt[i] + 1));   // +1 = self loop
}

__global__ __launch_bounds__(1024) void scan_kernel(const int* __restrict__ cnt,
                                                    int* __restrict__ row_off,
                                                    int* __restrict__ cursor, int n) {
    __shared__ int wavesums[16];
    int t = threadIdx.x;
    int chunk = (n + 1023) >> 10;
    int lo = t * chunk;
    int hi = min(lo + chunk, n);
    int s = 0;
    for (int i = lo; i < hi; ++i) s += cnt[i];
    // wave-inclusive scan
    int lane = t & 63, wid = t >> 6;
    int incl = s;
    #pragma unroll
    for (int off = 1; off < 64; off <<= 1) {
        int v = __shfl_up(incl, off);
        if (lane >= off) incl += v;
    }
    if (lane == 63) wavesums[wid] = incl;
    __syncthreads();
    if (t < 16) {
        int v = wavesums[t];
        int inc2 = v;
        #pragma unroll
        for (int off = 1; off < 16; off <<= 1) {
            int u = __shfl_up(inc2, off);
            if (t >= off) inc2 += u;
        }
        wavesums[t] = inc2 - v;   // exclusive wave offset
    }
    __syncthreads();
    int run = wavesums[wid] + (incl - s);   // exclusive prefix of this chunk
    for (int i = lo; i < hi; ++i) {
        int c = cnt[i];
        row_off[i] = run;
        cursor[i]  = run;
        run += c;
    }
    if (lo < n && hi == n) row_off[n] = run;
}

__global__ __launch_bounds__(256) void scatter_kernel(const int* __restrict__ src,
                                                      const int* __restrict__ dst,
                                                      int* __restrict__ cursor,
                                                      int* __restrict__ ssrc, int E) {
    int e = blockIdx.x * 256 + threadIdx.x;
    if (e < E) {
        int d = dst[e];
        int pos = atomicAdd(&cursor[d], 1);
        ssrc[pos] = src[e];
    }
}

// ---------------- BN fold ----------------

__global__ void prep_kernel(const float* __restrict__ b, const float* __restrict__ g,
                            const float* __restrict__ be, const float* __restrict__ m,
                            const float* __restrict__ v, float* __restrict__ sc,
                            float* __restrict__ sh) {
    int t = threadIdx.x;
    if (t < HDIM) {
        float s = g[t] * rsqrtf(v[t] + BN_EPS);
        sc[t] = s;
        sh[t] = (b[t] - m[t]) * s + be[t];
    }
}

// ---------------- aggregation: out[i] = inv[i]*(sum_nbr in[s]*inv[s] + in[i]*inv[i]) ----------------

template <int C>
__global__ __launch_bounds__(256) void agg_kernel(const float* __restrict__ in,
                                                  const float* __restrict__ inv,
                                                  const int* __restrict__ row_off,
                                                  const int* __restrict__ ssrc,
                                                  float* __restrict__ out, int n) {
    constexpr int C4 = C / 4;
    int wave = threadIdx.x >> 6;
    int lane = threadIdx.x & 63;
    int node = blockIdx.x * 4 + wave;
    if (node >= n) return;
    float inv_i = inv[node];
    float4 acc = make_float4(0.f, 0.f, 0.f, 0.f);
    if (lane < C4) {
        float4 v = ((const float4*)(in + (size_t)node * C))[lane];
        acc.x = v.x * inv_i; acc.y = v.y * inv_i; acc.z = v.z * inv_i; acc.w = v.w * inv_i;
    }
    int beg = row_off[node], end = row_off[node + 1];
    int j = beg;
    for (; j + 1 < end; j += 2) {   // unroll 2 for latency
        int s0 = ssrc[j], s1 = ssrc[j + 1];
        float w0 = inv[s0], w1 = inv[s1];
        if (lane < C4) {
            float4 v0 = ((const float4*)(in + (size_t)s0 * C))[lane];
            float4 v1 = ((const float4*)(in + (size_t)s1 * C))[lane];
            acc.x += v0.x * w0; acc.y += v0.y * w0; acc.z += v0.z * w0; acc.w += v0.w * w0;
            acc.x += v1.x * w1; acc.y += v1.y * w1; acc.z += v1.z * w1; acc.w += v1.w * w1;
        }
    }
    if (j < end) {
        int s0 = ssrc[j];
        float w0 = inv[s0];
        if (lane < C4) {
            float4 v0 = ((const float4*)(in + (size_t)s0 * C))[lane];
            acc.x += v0.x * w0; acc.y += v0.y * w0; acc.z += v0.z * w0; acc.w += v0.w * w0;
        }
    }
    if (lane < C4) {
        acc.x *= inv_i; acc.y *= inv_i; acc.z *= inv_i; acc.w *= inv_i;
        ((float4*)(out + (size_t)node * C))[lane] = acc;
    }
}

// ---------------- fp32 GEMM: C[n x 160] = relu( (A[n x K] @ B[K x 160]) * sc + sh ) ----------------

template <int K>
__global__ __launch_bounds__(256) void gemm_kernel(const float* __restrict__ A,
                                                   const float* __restrict__ B,
                                                   const float* __restrict__ sc,
                                                   const float* __restrict__ sh,
                                                   float* __restrict__ Cout, int n) {
    __shared__ float As[16 * 68];     // [k][row], padded 64->68 (2-way max conflict)
    __shared__ float Bs[16 * 160];    // [k][col]
    int tid = threadIdx.x;
    int row0 = blockIdx.x * 64;
    int tx = tid & 15, ty = tid >> 4;   // col group / row group
    int ar = tid >> 2, ak4 = tid & 3;   // staging: row / k-quad

    float acc[4][10];
    #pragma unroll
    for (int j = 0; j < 4; ++j)
        #pragma unroll
        for (int i = 0; i < 10; ++i) acc[j][i] = 0.f;

    float scv[10], shv[10];
    #pragma unroll
    for (int i = 0; i < 10; ++i) { scv[i] = sc[tx + 16 * i]; shv[i] = sh[tx + 16 * i]; }

    bool arow_ok = (row0 + ar) < n;
    const float* Arow = A + (size_t)(row0 + ar) * K;

    for (int k0 = 0; k0 < K; k0 += 16) {
        __syncthreads();
        float4 a = make_float4(0.f, 0.f, 0.f, 0.f);
        if (arow_ok) a = *(const float4*)(Arow + k0 + ak4 * 4);
        As[(ak4 * 4 + 0) * 68 + ar] = a.x;
        As[(ak4 * 4 + 1) * 68 + ar] = a.y;
        As[(ak4 * 4 + 2) * 68 + ar] = a.z;
        As[(ak4 * 4 + 3) * 68 + ar] = a.w;
        #pragma unroll
        for (int i = 0; i < 10; ++i)
            Bs[tid + 256 * i] = B[k0 * 160 + tid + 256 * i];
        __syncthreads();
        #pragma unroll
        for (int k = 0; k < 16; ++k) {
            float4 av = *(const float4*)&As[k * 68 + ty * 4];
            float bv[10];
            #pragma unroll
            for (int i = 0; i < 10; ++i) bv[i] = Bs[k * 160 + tx + 16 * i];
            #pragma unroll
            for (int i = 0; i < 10; ++i) {
                acc[0][i] += av.x * bv[i];
                acc[1][i] += av.y * bv[i];
                acc[2][i] += av.z * bv[i];
                acc[3][i] += av.w * bv[i];
            }
        }
    }
    #pragma unroll
    for (int j = 0; j < 4; ++j) {
        int r = row0 + ty * 4 + j;
        if (r < n) {
            #pragma unroll
            for (int i = 0; i < 10; ++i) {
                float v = acc[j][i] * scv[i] + shv[i];
                Cout[(size_t)r * 160 + tx + 16 * i] = fmaxf(v, 0.f);
            }
        }
    }
}

// ---------------- mean pool (sorted batch) + MLP head ----------------

__global__ __launch_bounds__(256) void pool_head_kernel(const float* __restrict__ h,
                                                        const int* __restrict__ batch,
                                                        const float* __restrict__ Wc1,
                                                        const float* __restrict__ bc1,
                                                        const float* __restrict__ Wc2,
                                                        const float* __restrict__ bc2,
                                                        float* __restrict__ out, int n) {
    __shared__ float pooled[160];
    __shared__ float z[80];
    __shared__ int range[2];
    int g = blockIdx.x;
    int t = threadIdx.x;
    if (t < 2) {
        int target = g + t;
        int lo = 0, hi = n;
        while (lo < hi) {
            int mid = (lo + hi) >> 1;
            if (batch[mid] < target) lo = mid + 1; else hi = mid;
        }
        range[t] = lo;
    }
    __syncthreads();
    int lo = range[0], hi = range[1];
    if (t < 160) {
        float s = 0.f;
        for (int r = lo; r < hi; ++r) s += h[(size_t)r * 160 + t];
        pooled[t] = s / fmaxf((float)(hi - lo), 1.f);
    }
    __syncthreads();
    if (t < 80) {
        float s = bc1[t];
        for (int k = 0; k < 160; ++k) s += pooled[k] * Wc1[k * 80 + t];
        z[t] = fmaxf(s, 0.f);
    }
    __syncthreads();
    if (t < 2) {
        float s = bc2[t];
        for (int k = 0; k < 80; ++k) s += z[k] * Wc2[k * 2 + t];
        out[g * 2 + t] = s;
    }
}

// ---------------- launch ----------------

static inline size_t align256(size_t x) { return (x + 255) & ~(size_t)255; }

extern "C" void kernel_launch(void* const* d_in, const int* in_sizes, int n_in,
                              void* d_out, int out_size, void* d_ws, size_t ws_size,
                              hipStream_t stream) {
    const float* x   = (const float*)d_in[0];
    const int* ei    = (const int*)d_in[1];
    const int* batch = (const int*)d_in[2];
    const float* W1  = (const float*)d_in[3];
    const float* b1  = (const float*)d_in[4];
    const float* W2  = (const float*)d_in[5];
    const float* b2  = (const float*)d_in[6];
    const float* W3  = (const float*)d_in[7];
    const float* b3  = (const float*)d_in[8];
    const float* g1  = (const float*)d_in[9];
    const float* be1 = (const float*)d_in[10];
    const float* m1  = (const float*)d_in[11];
    const float* v1  = (const float*)d_in[12];
    const float* g2  = (const float*)d_in[13];
    const float* be2 = (const float*)d_in[14];
    const float* m2  = (const float*)d_in[15];
    const float* v2  = (const float*)d_in[16];
    const float* g3  = (const float*)d_in[17];
    const float* be3 = (const float*)d_in[18];
    const float* m3  = (const float*)d_in[19];
    const float* v3  = (const float*)d_in[20];
    const float* Wc1 = (const float*)d_in[21];
    const float* bc1 = (const float*)d_in[22];
    const float* Wc2 = (const float*)d_in[23];
    const float* bc2 = (const float*)d_in[24];
    float* out = (float*)d_out;

    const int N = in_sizes[2];          // 50000
    const int E = in_sizes[1] / 2;      // 1600000
    const int* src = ei;
    const int* dst = ei + E;

    char* w = (char*)d_ws;
    int*   cnt     = (int*)w;             w += align256((size_t)N * 4);
    int*   row_off = (int*)w;             w += align256((size_t)(N + 1) * 4);
    int*   cursor  = (int*)w;             w += align256((size_t)N * 4);
    float* inv     = (float*)w;           w += align256((size_t)N * 4);
    int*   ssrc    = (int*)w;             w += align256((size_t)E * 4);
    float* scsh    = (float*)w;           w += align256((size_t)6 * HDIM * 4);
    float* bufA    = (float*)w;           w += align256((size_t)N * HDIM * 4);
    float* bufB    = (float*)w;           w += align256((size_t)N * HDIM * 4);
    float* sc1 = scsh, *sh1 = scsh + 160, *sc2 = scsh + 320, *sh2 = scsh + 480,
         * sc3 = scsh + 640, *sh3 = scsh + 800;

    hipMemsetAsync(cnt, 0, (size_t)N * 4, stream);

    int gE = (E + 255) / 256;
    int gN = (N + 255) / 256;
    hist_kernel<<<gE, 256, 0, stream>>>(dst, cnt, E);
    inv_kernel<<<gN, 256, 0, stream>>>(cnt, inv, N);
    scan_kernel<<<1, 1024, 0, stream>>>(cnt, row_off, cursor, N);
    scatter_kernel<<<gE, 256, 0, stream>>>(src, dst, cursor, ssrc, E);

    prep_kernel<<<1, 256, 0, stream>>>(b1, g1, be1, m1, v1, sc1, sh1);
    prep_kernel<<<1, 256, 0, stream>>>(b2, g2, be2, m2, v2, sc2, sh2);
    prep_kernel<<<1, 256, 0, stream>>>(b3, g3, be3, m3, v3, sc3, sh3);

    int gAgg = (N + 3) / 4;
    int gGemm = (N + 63) / 64;

    // layer 1: aggregate x (128 ch) then GEMM(K=128) + BN + ReLU
    agg_kernel<128><<<gAgg, 256, 0, stream>>>(x, inv, row_off, ssrc, bufA, N);
    gemm_kernel<128><<<gGemm, 256, 0, stream>>>(bufA, W1, sc1, sh1, bufB, N);
    // layer 2
    agg_kernel<160><<<gAgg, 256, 0, stream>>>(bufB, inv, row_off, ssrc, bufA, N);
    gemm_kernel<160><<<gGemm, 256, 0, stream>>>(bufA, W2, sc2, sh2, bufB, N);
    // layer 3
    agg_kernel<160><<<gAgg, 256, 0, stream>>>(bufB, inv, row_off, ssrc, bufA, N);
    gemm_kernel<160><<<gGemm, 256, 0, stream>>>(bufA, W3, sc3, sh3, bufB, N);

    pool_head_kernel<<<N_GRAPHS, 256, 0, stream>>>(bufB, batch, Wc1, bc1, Wc2, bc2, out, N);
}